// Round 12
// baseline (120.091 us; speedup 1.0000x reference)
//
#include <hip/hip_runtime.h>
#include <math.h>

#define N_CELLS_C 100000
#define N_ISO_C 16
#define KP1_C 31
#define BLOCK 256

typedef float f32x4 __attribute__((ext_vector_type(4)));   // clang vector: OK for nontemporal builtins

// Per-wave index-dtype detect: int64 indices (< 2^17) have all odd int32
// words == 0; int32 random indices make that astronomically unlikely.
__device__ __forceinline__ int idx_shift(const char* idx_bytes) {
    const int lane = threadIdx.x & 63;
    int probe = 0;
    if (lane < 16) probe = ((const int*)idx_bytes)[2 * lane + 1];
    return __any(probe != 0) ? 2 : 3;   // log2(bytes per index)
}

// 14-bit float = fp16 with low 2 mantissa bits dropped (round-to-nearest).
__device__ __forceinline__ unsigned enc14(float x) {
    const _Float16 h = (_Float16)x;
    const unsigned short b = __builtin_bit_cast(unsigned short, h);
    return (((unsigned)b + 2u) >> 2) & 0x3FFFu;
}
__device__ __forceinline__ float dec14(unsigned v) {
    const unsigned short b = (unsigned short)(v << 2);
    const _Float16 h = __builtin_bit_cast(_Float16, b);
    return (float)h;
}

// Record: 32B, two INDEPENDENT 16B halves.
//   half0 (words 0-3): dims 0..8   (9 x 14b = 126b)
//   half1 (words 4-7): dims 9..15, u  (8 x 14b = 112b; slot 8 zero)
// 2 threads per cell; thread h packs half h (halves are independent).
__global__ __launch_bounds__(BLOCK) void pack_kernel(
    const float* __restrict__ unsplice,
    const float* __restrict__ splices,
    unsigned* __restrict__ rec)
{
    const int t = blockIdx.x * BLOCK + threadIdx.x;
    const int cell = t >> 1, h = t & 1;
    if (cell >= N_CELLS_C) return;
    const f32x4* row = (const f32x4*)(splices + (long long)cell * N_ISO_C);
    unsigned w[4] = {0, 0, 0, 0};
    if (h == 0) {
        const f32x4 r0 = row[0], r1 = row[1];
        const float c2 = *(splices + (long long)cell * N_ISO_C + 8);
        const float h0[9] = { r0.x, r0.y, r0.z, r0.w, r1.x, r1.y, r1.z, r1.w, c2 };
        #pragma unroll
        for (int i = 0; i < 9; ++i) {
            const unsigned v = enc14(h0[i]);
            const int s = 14 * i, k = s >> 5, off = s & 31;
            w[k] |= v << off;
            if (off > 18 && k < 3) w[k + 1] |= v >> (32 - off);
        }
        // i=8: s=112, k=3, off=16 -> fits in w[3], no spill
    } else {
        const f32x4 r2 = row[2], r3 = row[3];
        const float h1[8] = { r2.y, r2.z, r2.w, r3.x, r3.y, r3.z, r3.w,
                              unsplice[cell] };
        #pragma unroll
        for (int i = 0; i < 8; ++i) {
            const unsigned v = enc14(h1[i]);
            const int s = 14 * i, k = s >> 5, off = s & 31;
            w[k] |= v << off;
            if (off > 18 && k < 3) w[k + 1] |= v >> (32 - off);
        }
        // i=7: s=98, k=3, off=2 -> fits, no spill
    }
    *(uint4*)(rec + (size_t)cell * 8 + 4 * h) = uint4{w[0], w[1], w[2], w[3]};
}

// 8 lanes/cell = 4 pairs. Pair p owns neighbors k = 1+p+4t (t=0..7, clamped);
// lane w of the pair loads/decodes the 16B half w. Streaming reads (idx,
// center rows, scalars) are NONTEMPORAL so they don't evict the rec gather
// set from per-XCD L2; rec loads stay fully cached.
__global__ __launch_bounds__(BLOCK, 8) void cost_kernel(
    const float* __restrict__ unsplice,
    const float* __restrict__ splices,
    const float* __restrict__ unsplice_predict,
    const float* __restrict__ splice_predicts,
    const char*  __restrict__ idx_bytes,
    const unsigned* __restrict__ rec,
    float*       __restrict__ partials)
{
    const int tid  = threadIdx.x;
    const int sub  = tid & 7;
    const int w    = sub & 1;
    const int p    = sub >> 1;
    const int cell = blockIdx.x * (BLOCK / 8) + (tid >> 3);   // grid exact: 3125*32
    const int shift = idx_shift(idx_bytes);

    // Center half in fp32 (exact), 9 slots; half1 slot 8 = 0.
    float ci[9], v[9];
    {
        const f32x4* sr = (const f32x4*)(splices         + (long long)cell * N_ISO_C);
        const f32x4* pr = (const f32x4*)(splice_predicts + (long long)cell * N_ISO_C);
        if (w == 0) {
            const f32x4 a  = __builtin_nontemporal_load(sr + 0);
            const f32x4 b  = __builtin_nontemporal_load(sr + 1);
            const f32x4 pa = __builtin_nontemporal_load(pr + 0);
            const f32x4 pb = __builtin_nontemporal_load(pr + 1);
            const float c2  = __builtin_nontemporal_load(splices         + (long long)cell * N_ISO_C + 8);
            const float pc2 = __builtin_nontemporal_load(splice_predicts + (long long)cell * N_ISO_C + 8);
            ci[0]=a.x; ci[1]=a.y; ci[2]=a.z; ci[3]=a.w;
            ci[4]=b.x; ci[5]=b.y; ci[6]=b.z; ci[7]=b.w; ci[8]=c2;
            v[0]=pa.x-a.x; v[1]=pa.y-a.y; v[2]=pa.z-a.z; v[3]=pa.w-a.w;
            v[4]=pb.x-b.x; v[5]=pb.y-b.y; v[6]=pb.z-b.z; v[7]=pb.w-b.w; v[8]=pc2-c2;
        } else {
            const f32x4 a  = __builtin_nontemporal_load(sr + 2);
            const f32x4 b  = __builtin_nontemporal_load(sr + 3);
            const f32x4 pa = __builtin_nontemporal_load(pr + 2);
            const f32x4 pb = __builtin_nontemporal_load(pr + 3);
            const float u   = __builtin_nontemporal_load(unsplice + cell);
            const float up  = __builtin_nontemporal_load(unsplice_predict + cell);
            ci[0]=a.y; ci[1]=a.z; ci[2]=a.w;
            ci[3]=b.x; ci[4]=b.y; ci[5]=b.z; ci[6]=b.w; ci[7]=u; ci[8]=0.f;
            v[0]=pa.y-a.y; v[1]=pa.z-a.z; v[2]=pa.w-a.w;
            v[3]=pb.x-b.x; v[4]=pb.y-b.y; v[5]=pb.z-b.z; v[6]=pb.w-b.w;
            v[7]=up-u; v[8]=0.f;
        }
    }
    float vp = 0.f;
    #pragma unroll
    for (int i = 0; i < 9; ++i) vp = fmaf(v[i], v[i], vp);
    vp += __shfl_xor(vp, 1);
    const float inv_vi = (vp > 0.f) ? rsqrtf(vp) : 0.f;   // zero-norm -> 0 (ref: denom->1, dot 0)

    const long long base = (long long)cell * KP1_C;
    int jv[8];
    #pragma unroll
    for (int t = 0; t < 8; ++t) {
        int k = 1 + p + 4 * t;
        if (k > 30) k = 30;                    // duplicate (safe under max)
        jv[t] = __builtin_nontemporal_load(
            (const int*)(idx_bytes + ((base + k) << shift)));
    }

    float maxq = -INFINITY;
    #pragma unroll
    for (int c2 = 0; c2 < 2; ++c2) {
        uint4 G[4];
        #pragma unroll
        for (int t = 0; t < 4; ++t)            // cached gather (keep in L2!)
            G[t] = *(const uint4*)(rec + (size_t)jv[c2 * 4 + t] * 8 + 4 * w);
        #pragma unroll
        for (int t = 0; t < 4; ++t) {
            const unsigned wd[4] = { G[t].x, G[t].y, G[t].z, G[t].w };
            float dp = 0.f, np = 0.f;
            #pragma unroll
            for (int i = 0; i < 9; ++i) {
                const int s = 14 * i, k = s >> 5, off = s & 31;
                unsigned raw = wd[k] >> off;
                if (off > 18) raw |= wd[k + 1] << (32 - off);
                const float g = dec14(raw & 0x3FFFu);
                const float d = g - ci[i];
                dp = fmaf(v[i], d, dp);
                np = fmaf(d, d, np);
            }
            dp += __shfl_xor(dp, 1);
            np += __shfl_xor(np, 1);
            const float rn = (np > 0.f) ? rsqrtf(np) : 0.f;
            maxq = fmaxf(maxq, dp * rn);
        }
    }
    maxq = fmaxf(maxq, __shfl_xor(maxq, 2));
    maxq = fmaxf(maxq, __shfl_xor(maxq, 4));
    float cost = (sub == 0) ? (1.0f - maxq * inv_vi) : 0.f;

    // block tree-sum (deterministic) -> partials; separate final reduce (no atomics)
    for (int off = 32; off > 0; off >>= 1) cost += __shfl_down(cost, off);
    __shared__ float wsum[BLOCK / 64];
    if ((tid & 63) == 0) wsum[tid >> 6] = cost;
    __syncthreads();
    if (tid == 0) {
        float s = 0.f;
        #pragma unroll
        for (int wv = 0; wv < BLOCK / 64; ++wv) s += wsum[wv];
        partials[blockIdx.x] = s;
    }
}

// -------- fp32 fallback (used only if ws_size is too small) -------
__global__ __launch_bounds__(BLOCK) void cost_kernel_f32(
    const float* __restrict__ unsplice,
    const float* __restrict__ splices,
    const float* __restrict__ unsplice_predict,
    const float* __restrict__ splice_predicts,
    const char*  __restrict__ idx_bytes,
    float*       __restrict__ partials)
{
    const int tid  = threadIdx.x;
    const int q    = tid & 3;
    const int cell = blockIdx.x * (BLOCK / 4) + (tid >> 2);
    const int shift = idx_shift(idx_bytes);

    float cost = 0.0f;
    if (cell < N_CELLS_C) {
        const float u_i = unsplice[cell];
        const float uv  = unsplice_predict[cell] - u_i;
        const float4 s4  = *(const float4*)(splices         + (long long)cell * N_ISO_C + 4 * q);
        const float4 sp4 = *(const float4*)(splice_predicts + (long long)cell * N_ISO_C + 4 * q);
        const float v0 = sp4.x - s4.x, v1 = sp4.y - s4.y, v2 = sp4.z - s4.z, v3 = sp4.w - s4.w;
        float vpp = v0*v0 + v1*v1 + v2*v2 + v3*v3;
        vpp += __shfl_xor(vpp, 1);
        vpp += __shfl_xor(vpp, 2);
        const float vn2 = vpp + uv * uv;
        const float inv_vi = (vn2 > 0.0f) ? rsqrtf(vn2) : 0.0f;
        const long long base = (long long)cell * KP1_C;
        float maxq = -INFINITY;
        #pragma unroll
        for (int k = 1; k < KP1_C; ++k) {
            const int j = *(const int*)(idx_bytes + ((base + k) << shift));
            const float unj = unsplice[j];
            const float4 n4 = *(const float4*)(splices + (long long)j * N_ISO_C + 4 * q);
            const float d0 = n4.x - s4.x, d1 = n4.y - s4.y, d2 = n4.z - s4.z, d3 = n4.w - s4.w;
            float dp = v0*d0 + v1*d1 + v2*d2 + v3*d3;
            float np = d0*d0 + d1*d1 + d2*d2 + d3*d3;
            dp += __shfl_xor(dp, 1);  np += __shfl_xor(np, 1);
            dp += __shfl_xor(dp, 2);  np += __shfl_xor(np, 2);
            const float un  = unj - u_i;
            const float dot = dp + uv * un;
            const float nn2 = np + un * un;
            const float rn  = (nn2 > 0.0f) ? rsqrtf(nn2) : 0.0f;
            maxq = fmaxf(maxq, dot * rn);
        }
        if (q == 0) cost = 1.0f - maxq * inv_vi;
    }
    for (int off = 32; off > 0; off >>= 1) cost += __shfl_down(cost, off);
    __shared__ float wsum[BLOCK / 64];
    if ((tid & 63) == 0) wsum[tid >> 6] = cost;
    __syncthreads();
    if (tid == 0) {
        float s = 0.0f;
        #pragma unroll
        for (int wv = 0; wv < BLOCK / 64; ++wv) s += wsum[wv];
        partials[blockIdx.x] = s;
    }
}

__global__ __launch_bounds__(BLOCK) void final_reduce_kernel(
    const float* __restrict__ partials, int nparts, float* __restrict__ out)
{
    float s = 0.0f;
    for (int i = threadIdx.x; i < nparts; i += BLOCK) s += partials[i];
    for (int off = 32; off > 0; off >>= 1) s += __shfl_down(s, off);
    __shared__ float wsum[BLOCK / 64];
    if ((threadIdx.x & 63) == 0) wsum[threadIdx.x >> 6] = s;
    __syncthreads();
    if (threadIdx.x == 0) {
        float t = 0.0f;
        #pragma unroll
        for (int wv = 0; wv < BLOCK / 64; ++wv) t += wsum[wv];
        out[0] = t / (float)N_CELLS_C;
    }
}

extern "C" void kernel_launch(void* const* d_in, const int* in_sizes, int n_in,
                              void* d_out, int out_size, void* d_ws, size_t ws_size,
                              hipStream_t stream) {
    const float* unsplice         = (const float*)d_in[0];
    const float* splices          = (const float*)d_in[1];
    const float* unsplice_predict = (const float*)d_in[2];
    const float* splice_predicts  = (const float*)d_in[3];
    const char*  idx_bytes        = (const char*)d_in[4];
    float* out = (float*)d_out;

    // ws layout: [rec 3.2MB][partials]
    unsigned* rec      = (unsigned*)d_ws;
    float*    partials = (float*)((char*)d_ws + 3200000);

    const size_t req = 3200000 + 16 * 4096;

    if (ws_size >= req) {
        const int pack_blocks = (2 * N_CELLS_C + BLOCK - 1) / BLOCK;  // 782
        pack_kernel<<<pack_blocks, BLOCK, 0, stream>>>(unsplice, splices, rec);
        const int nblocks = N_CELLS_C / (BLOCK / 8);                  // 3125, exact
        cost_kernel<<<nblocks, BLOCK, 0, stream>>>(
            unsplice, splices, unsplice_predict, splice_predicts,
            idx_bytes, rec, partials);
        final_reduce_kernel<<<1, BLOCK, 0, stream>>>(partials, nblocks, out);
    } else {
        float* fb_partials = (float*)d_ws;
        const int nblocks = (N_CELLS_C + (BLOCK / 4) - 1) / (BLOCK / 4);
        cost_kernel_f32<<<nblocks, BLOCK, 0, stream>>>(
            unsplice, splices, unsplice_predict, splice_predicts,
            idx_bytes, fb_partials);
        final_reduce_kernel<<<1, BLOCK, 0, stream>>>(fb_partials, nblocks, out);
    }
}

// Round 13
// 39.405 us; speedup vs baseline: 3.0476x; 3.0476x over previous
//
#include <hip/hip_runtime.h>
#include <math.h>

#define N_CELLS_C 100000
#define N_ISO_C 16
#define KP1_C 31
#define BLOCK 256

// Per-wave index-dtype detect: int64 indices (< 2^17) have all odd int32
// words == 0; int32 random indices make that astronomically unlikely.
__device__ __forceinline__ int idx_shift(const char* idx_bytes) {
    const int lane = threadIdx.x & 63;
    int probe = 0;
    if (lane < 16) probe = ((const int*)idx_bytes)[2 * lane + 1];
    return __any(probe != 0) ? 2 : 3;   // log2(bytes per index)
}

// 14-bit float = fp16 with low 2 mantissa bits dropped (round-to-nearest).
__device__ __forceinline__ unsigned enc14(float x) {
    const _Float16 h = (_Float16)x;
    const unsigned short b = __builtin_bit_cast(unsigned short, h);
    return (((unsigned)b + 2u) >> 2) & 0x3FFFu;
}
__device__ __forceinline__ float dec14(unsigned v) {
    const unsigned short b = (unsigned short)(v << 2);
    const _Float16 h = __builtin_bit_cast(_Float16, b);
    return (float)h;
}

// Record: 32B, two INDEPENDENT 16B halves.
//   half0 (words 0-3): dims 0..8   (9 x 14b = 126b)
//   half1 (words 4-7): dims 9..15, u  (8 x 14b = 112b; slot 8 zero)
// 2 threads per cell; thread h packs half h (halves are independent).
__global__ __launch_bounds__(BLOCK) void pack_kernel(
    const float* __restrict__ unsplice,
    const float* __restrict__ splices,
    unsigned* __restrict__ rec)
{
    const int t = blockIdx.x * BLOCK + threadIdx.x;
    const int cell = t >> 1, h = t & 1;
    if (cell >= N_CELLS_C) return;
    const float4* row = (const float4*)(splices + (long long)cell * N_ISO_C);
    unsigned w[4] = {0, 0, 0, 0};
    if (h == 0) {
        const float4 r0 = row[0], r1 = row[1];
        const float c2 = *(splices + (long long)cell * N_ISO_C + 8);
        const float h0[9] = { r0.x, r0.y, r0.z, r0.w, r1.x, r1.y, r1.z, r1.w, c2 };
        #pragma unroll
        for (int i = 0; i < 9; ++i) {
            const unsigned v = enc14(h0[i]);
            const int s = 14 * i, k = s >> 5, off = s & 31;
            w[k] |= v << off;
            if (off > 18 && k < 3) w[k + 1] |= v >> (32 - off);
        }
        // i=8: s=112, k=3, off=16 -> fits in w[3], no spill
    } else {
        const float4 r2 = row[2], r3 = row[3];
        const float h1[8] = { r2.y, r2.z, r2.w, r3.x, r3.y, r3.z, r3.w,
                              unsplice[cell] };
        #pragma unroll
        for (int i = 0; i < 8; ++i) {
            const unsigned v = enc14(h1[i]);
            const int s = 14 * i, k = s >> 5, off = s & 31;
            w[k] |= v << off;
            if (off > 18 && k < 3) w[k + 1] |= v >> (32 - off);
        }
        // i=7: s=98, k=3, off=2 -> fits, no spill
    }
    *(uint4*)(rec + (size_t)cell * 8 + 4 * h) = uint4{w[0], w[1], w[2], w[3]};
}

// 8 lanes/cell = 4 pairs. Pair p owns neighbors k = 1+p+4t (t=0..7, clamped);
// lane w of the pair loads/decodes the 16B half w. All 8 half-record gathers
// issued in one batch (8 misses in flight per lane); all loads normally
// cached (nontemporal hints proven harmful on this access pattern, R6/R12).
__global__ __launch_bounds__(BLOCK, 8) void cost_kernel(
    const float* __restrict__ unsplice,
    const float* __restrict__ splices,
    const float* __restrict__ unsplice_predict,
    const float* __restrict__ splice_predicts,
    const char*  __restrict__ idx_bytes,
    const unsigned* __restrict__ rec,
    float*       __restrict__ partials)
{
    const int tid  = threadIdx.x;
    const int sub  = tid & 7;
    const int w    = sub & 1;
    const int p    = sub >> 1;
    const int cell = blockIdx.x * (BLOCK / 8) + (tid >> 3);   // grid exact: 3125*32
    const int shift = idx_shift(idx_bytes);

    // Center half in fp32 (exact), 9 slots; half1 slot 8 = 0.
    float ci[9], v[9];
    {
        const float4* sr = (const float4*)(splices         + (long long)cell * N_ISO_C);
        const float4* pr = (const float4*)(splice_predicts + (long long)cell * N_ISO_C);
        if (w == 0) {
            const float4 a = sr[0], b = sr[1]; const float c2 = sr[2].x;
            const float4 pa = pr[0], pb = pr[1]; const float pc2 = pr[2].x;
            ci[0]=a.x; ci[1]=a.y; ci[2]=a.z; ci[3]=a.w;
            ci[4]=b.x; ci[5]=b.y; ci[6]=b.z; ci[7]=b.w; ci[8]=c2;
            v[0]=pa.x-a.x; v[1]=pa.y-a.y; v[2]=pa.z-a.z; v[3]=pa.w-a.w;
            v[4]=pb.x-b.x; v[5]=pb.y-b.y; v[6]=pb.z-b.z; v[7]=pb.w-b.w; v[8]=pc2-c2;
        } else {
            const float4 a = sr[2], b = sr[3];
            const float4 pa = pr[2], pb = pr[3];
            const float u  = unsplice[cell], up = unsplice_predict[cell];
            ci[0]=a.y; ci[1]=a.z; ci[2]=a.w;
            ci[3]=b.x; ci[4]=b.y; ci[5]=b.z; ci[6]=b.w; ci[7]=u; ci[8]=0.f;
            v[0]=pa.y-a.y; v[1]=pa.z-a.z; v[2]=pa.w-a.w;
            v[3]=pb.x-b.x; v[4]=pb.y-b.y; v[5]=pb.z-b.z; v[6]=pb.w-b.w;
            v[7]=up-u; v[8]=0.f;
        }
    }
    float vp = 0.f;
    #pragma unroll
    for (int i = 0; i < 9; ++i) vp = fmaf(v[i], v[i], vp);
    vp += __shfl_xor(vp, 1);
    const float inv_vi = (vp > 0.f) ? rsqrtf(vp) : 0.f;   // zero-norm -> 0 (ref: denom->1, dot 0)

    const long long base = (long long)cell * KP1_C;
    int jv[8];
    #pragma unroll
    for (int t = 0; t < 8; ++t) {
        int k = 1 + p + 4 * t;
        if (k > 30) k = 30;                    // duplicate (safe under max)
        jv[t] = *(const int*)(idx_bytes + ((base + k) << shift));
    }

    // All 8 half-record gathers in flight.
    uint4 G[8];
    #pragma unroll
    for (int t = 0; t < 8; ++t)
        G[t] = *(const uint4*)(rec + (size_t)jv[t] * 8 + 4 * w);

    float maxq = -INFINITY;
    #pragma unroll
    for (int t = 0; t < 8; ++t) {
        const unsigned wd[4] = { G[t].x, G[t].y, G[t].z, G[t].w };
        float dp = 0.f, np = 0.f;
        #pragma unroll
        for (int i = 0; i < 9; ++i) {
            const int s = 14 * i, k = s >> 5, off = s & 31;
            unsigned raw = wd[k] >> off;
            if (off > 18) raw |= wd[k + 1] << (32 - off);
            const float g = dec14(raw & 0x3FFFu);
            const float d = g - ci[i];
            dp = fmaf(v[i], d, dp);
            np = fmaf(d, d, np);
        }
        dp += __shfl_xor(dp, 1);
        np += __shfl_xor(np, 1);
        const float rn = (np > 0.f) ? rsqrtf(np) : 0.f;
        maxq = fmaxf(maxq, dp * rn);
    }
    maxq = fmaxf(maxq, __shfl_xor(maxq, 2));
    maxq = fmaxf(maxq, __shfl_xor(maxq, 4));
    float cost = (sub == 0) ? (1.0f - maxq * inv_vi) : 0.f;

    // block tree-sum (deterministic) -> partials; separate final reduce (no atomics)
    for (int off = 32; off > 0; off >>= 1) cost += __shfl_down(cost, off);
    __shared__ float wsum[BLOCK / 64];
    if ((tid & 63) == 0) wsum[tid >> 6] = cost;
    __syncthreads();
    if (tid == 0) {
        float s = 0.f;
        #pragma unroll
        for (int wv = 0; wv < BLOCK / 64; ++wv) s += wsum[wv];
        partials[blockIdx.x] = s;
    }
}

// -------- fp32 fallback (used only if ws_size is too small) -------
__global__ __launch_bounds__(BLOCK) void cost_kernel_f32(
    const float* __restrict__ unsplice,
    const float* __restrict__ splices,
    const float* __restrict__ unsplice_predict,
    const float* __restrict__ splice_predicts,
    const char*  __restrict__ idx_bytes,
    float*       __restrict__ partials)
{
    const int tid  = threadIdx.x;
    const int q    = tid & 3;
    const int cell = blockIdx.x * (BLOCK / 4) + (tid >> 2);
    const int shift = idx_shift(idx_bytes);

    float cost = 0.0f;
    if (cell < N_CELLS_C) {
        const float u_i = unsplice[cell];
        const float uv  = unsplice_predict[cell] - u_i;
        const float4 s4  = *(const float4*)(splices         + (long long)cell * N_ISO_C + 4 * q);
        const float4 sp4 = *(const float4*)(splice_predicts + (long long)cell * N_ISO_C + 4 * q);
        const float v0 = sp4.x - s4.x, v1 = sp4.y - s4.y, v2 = sp4.z - s4.z, v3 = sp4.w - s4.w;
        float vpp = v0*v0 + v1*v1 + v2*v2 + v3*v3;
        vpp += __shfl_xor(vpp, 1);
        vpp += __shfl_xor(vpp, 2);
        const float vn2 = vpp + uv * uv;
        const float inv_vi = (vn2 > 0.0f) ? rsqrtf(vn2) : 0.0f;
        const long long base = (long long)cell * KP1_C;
        float maxq = -INFINITY;
        #pragma unroll
        for (int k = 1; k < KP1_C; ++k) {
            const int j = *(const int*)(idx_bytes + ((base + k) << shift));
            const float unj = unsplice[j];
            const float4 n4 = *(const float4*)(splices + (long long)j * N_ISO_C + 4 * q);
            const float d0 = n4.x - s4.x, d1 = n4.y - s4.y, d2 = n4.z - s4.z, d3 = n4.w - s4.w;
            float dp = v0*d0 + v1*d1 + v2*d2 + v3*d3;
            float np = d0*d0 + d1*d1 + d2*d2 + d3*d3;
            dp += __shfl_xor(dp, 1);  np += __shfl_xor(np, 1);
            dp += __shfl_xor(dp, 2);  np += __shfl_xor(np, 2);
            const float un  = unj - u_i;
            const float dot = dp + uv * un;
            const float nn2 = np + un * un;
            const float rn  = (nn2 > 0.0f) ? rsqrtf(nn2) : 0.0f;
            maxq = fmaxf(maxq, dot * rn);
        }
        if (q == 0) cost = 1.0f - maxq * inv_vi;
    }
    for (int off = 32; off > 0; off >>= 1) cost += __shfl_down(cost, off);
    __shared__ float wsum[BLOCK / 64];
    if ((tid & 63) == 0) wsum[tid >> 6] = cost;
    __syncthreads();
    if (tid == 0) {
        float s = 0.0f;
        #pragma unroll
        for (int wv = 0; wv < BLOCK / 64; ++wv) s += wsum[wv];
        partials[blockIdx.x] = s;
    }
}

__global__ __launch_bounds__(BLOCK) void final_reduce_kernel(
    const float* __restrict__ partials, int nparts, float* __restrict__ out)
{
    float s = 0.0f;
    for (int i = threadIdx.x; i < nparts; i += BLOCK) s += partials[i];
    for (int off = 32; off > 0; off >>= 1) s += __shfl_down(s, off);
    __shared__ float wsum[BLOCK / 64];
    if ((threadIdx.x & 63) == 0) wsum[threadIdx.x >> 6] = s;
    __syncthreads();
    if (threadIdx.x == 0) {
        float t = 0.0f;
        #pragma unroll
        for (int wv = 0; wv < BLOCK / 64; ++wv) t += wsum[wv];
        out[0] = t / (float)N_CELLS_C;
    }
}

extern "C" void kernel_launch(void* const* d_in, const int* in_sizes, int n_in,
                              void* d_out, int out_size, void* d_ws, size_t ws_size,
                              hipStream_t stream) {
    const float* unsplice         = (const float*)d_in[0];
    const float* splices          = (const float*)d_in[1];
    const float* unsplice_predict = (const float*)d_in[2];
    const float* splice_predicts  = (const float*)d_in[3];
    const char*  idx_bytes        = (const char*)d_in[4];
    float* out = (float*)d_out;

    // ws layout: [rec 3.2MB][partials]
    unsigned* rec      = (unsigned*)d_ws;
    float*    partials = (float*)((char*)d_ws + 3200000);

    const size_t req = 3200000 + 16 * 4096;

    if (ws_size >= req) {
        const int pack_blocks = (2 * N_CELLS_C + BLOCK - 1) / BLOCK;  // 782
        pack_kernel<<<pack_blocks, BLOCK, 0, stream>>>(unsplice, splices, rec);
        const int nblocks = N_CELLS_C / (BLOCK / 8);                  // 3125, exact
        cost_kernel<<<nblocks, BLOCK, 0, stream>>>(
            unsplice, splices, unsplice_predict, splice_predicts,
            idx_bytes, rec, partials);
        final_reduce_kernel<<<1, BLOCK, 0, stream>>>(partials, nblocks, out);
    } else {
        float* fb_partials = (float*)d_ws;
        const int nblocks = (N_CELLS_C + (BLOCK / 4) - 1) / (BLOCK / 4);
        cost_kernel_f32<<<nblocks, BLOCK, 0, stream>>>(
            unsplice, splices, unsplice_predict, splice_predicts,
            idx_bytes, fb_partials);
        final_reduce_kernel<<<1, BLOCK, 0, stream>>>(fb_partials, nblocks, out);
    }
}